// Round 1
// baseline (216.099 us; speedup 1.0000x reference)
//
#include <hip/hip_runtime.h>

#define KK 8
#define NA 8
#define NB 64
#define NH 256
#define NW 256
#define HP (NH - KK + 1)   // 249
#define WP (NW - KK + 1)   // 249

// Stage 1: sm[a][y][x] = exp( (1/64) * sum_b x[a][b][y][x] )
// One thread per 4 consecutive pixels (float4), loop over 64 channels.
// Channel stride = NH*NW floats; every load is a fully-coalesced 16B/lane.
__global__ __launch_bounds__(256) void k_mean_exp(const float* __restrict__ x,
                                                 float* __restrict__ sm) {
    int tid = blockIdx.x * blockDim.x + threadIdx.x;       // 0 .. A*H*W/4-1
    int a = tid >> 14;                                     // H*W/4 = 16384 per image
    int p4 = (tid & 16383);                                // float4 index within image
    const float4* xp = (const float4*)(x + (size_t)a * NB * NH * NW) + p4;
    const int cs = NH * NW / 4;                            // channel stride in float4
    float4 acc = {0.f, 0.f, 0.f, 0.f};
    #pragma unroll 8
    for (int b = 0; b < NB; ++b) {
        float4 v = xp[(size_t)b * cs];
        acc.x += v.x; acc.y += v.y; acc.z += v.z; acc.w += v.w;
    }
    const float s = 1.0f / NB;
    float4 r;
    r.x = __expf(acc.x * s);
    r.y = __expf(acc.y * s);
    r.z = __expf(acc.z * s);
    r.w = __expf(acc.w * s);
    ((float4*)sm)[tid] = r;
}

// Stage 2: t[a][ph][pw] = local_count[a][ph][pw] / sum_{8x8 window} sm
// sm is 2 MB total -> L2-resident; naive 64-read window is fine.
__global__ __launch_bounds__(256) void k_sc_t(const float* __restrict__ sm,
                                              const float* __restrict__ c,
                                              float* __restrict__ t) {
    int tid = blockIdx.x * blockDim.x + threadIdx.x;
    if (tid >= NA * HP * WP) return;
    int a = tid / (HP * WP);
    int rem = tid - a * (HP * WP);
    int ph = rem / WP;
    int pw = rem - ph * WP;
    const float* s = sm + ((size_t)a * NH + ph) * NW + pw;
    float sum = 0.f;
    #pragma unroll
    for (int i = 0; i < KK; ++i) {
        #pragma unroll
        for (int j = 0; j < KK; ++j) sum += s[i * NW + j];
    }
    t[tid] = c[tid] / sum;
}

// Stage 3: out[a][y][x] = sm[a][y][x] * sum_{ph in [y-7,y], pw in [x-7,x], clamped} t[a][ph][pw]
__global__ __launch_bounds__(256) void k_out(const float* __restrict__ sm,
                                             const float* __restrict__ t,
                                             float* __restrict__ out) {
    int tid = blockIdx.x * blockDim.x + threadIdx.x;   // A*H*W threads
    int a = tid >> 16;
    int rem = tid & 65535;
    int y = rem >> 8;
    int x = rem & 255;
    int ph0 = y - (KK - 1); if (ph0 < 0) ph0 = 0;
    int ph1 = y; if (ph1 > HP - 1) ph1 = HP - 1;
    int pw0 = x - (KK - 1); if (pw0 < 0) pw0 = 0;
    int pw1 = x; if (pw1 > WP - 1) pw1 = WP - 1;
    const float* tp = t + (size_t)a * HP * WP;
    float sum = 0.f;
    for (int ph = ph0; ph <= ph1; ++ph) {
        const float* row = tp + ph * WP;
        for (int pw = pw0; pw <= pw1; ++pw) sum += row[pw];
    }
    out[tid] = sm[tid] * sum;
}

extern "C" void kernel_launch(void* const* d_in, const int* in_sizes, int n_in,
                              void* d_out, int out_size, void* d_ws, size_t ws_size,
                              hipStream_t stream) {
    const float* x = (const float*)d_in[0];        // (8,64,256,256) f32
    const float* c = (const float*)d_in[1];        // (8,1,249,249)  f32
    float* out = (float*)d_out;                    // (8,1,256,256)  f32
    float* sm = (float*)d_ws;                      // A*H*W floats = 2 MB
    float* t  = sm + (size_t)NA * NH * NW;         // A*HP*WP floats ~1.9 MB

    // Stage 1: A*H*W/4 = 131072 threads
    k_mean_exp<<<(NA * NH * NW / 4) / 256, 256, 0, stream>>>(x, sm);
    // Stage 2: A*HP*WP = 496008 threads
    k_sc_t<<<(NA * HP * WP + 255) / 256, 256, 0, stream>>>(sm, c, t);
    // Stage 3: A*H*W = 524288 threads
    k_out<<<(NA * NH * NW) / 256, 256, 0, stream>>>(sm, t, out);
}

// Round 2
// 201.274 us; speedup vs baseline: 1.0737x; 1.0737x over previous
//
#include <hip/hip_runtime.h>

#define KK 8
#define NA 8
#define NB 64
#define NH 256
#define NW 256
#define HP (NH - KK + 1)   // 249
#define WP (NW - KK + 1)   // 249
#define QSTRIDE (NA * NH * NW)   // floats per channel-quarter partial plane (524288)

// Stage 1: partial channel sums. 4 channel-quarters x (A*H*W/4) float4 threads.
// 2048 blocks -> 32 waves/CU: full latency hiding. Each thread: 16 coalesced
// float4 loads (16B/lane), one float4 store of the partial sum.
__global__ __launch_bounds__(256) void k_partial(const float* __restrict__ x,
                                                 float* __restrict__ ps) {
    int tid = blockIdx.x * 256 + threadIdx.x;   // 0 .. 524287
    int q   = tid >> 17;                        // channel quarter (8*16384 = 2^17)
    int rem = tid & 131071;
    int a   = rem >> 14;                        // H*W/4 = 16384 float4 per image
    int p4  = rem & 16383;
    const float4* xp = (const float4*)(x + ((size_t)a * NB + q * 16) * (NH * NW)) + p4;
    float4 acc = {0.f, 0.f, 0.f, 0.f};
    #pragma unroll
    for (int b = 0; b < 16; ++b) {
        float4 v = xp[(size_t)b * (NH * NW / 4)];
        acc.x += v.x; acc.y += v.y; acc.z += v.z; acc.w += v.w;
    }
    ((float4*)ps)[tid] = acc;   // float offset 4*tid = q*QSTRIDE + a*65536 + pixel
}

// Stage 2 (fused): per 32x32 output tile:
//   sm tile (46x46, incl. 7-halo) = exp(sum4/64) into LDS, then separable box
//   sums in LDS: hrs (horizontal 8-sum), t = c/sc with OOB zeroed, vs (vertical
//   8-sum of t), out = sm_center * horizontal 8-sum of vs.
__global__ __launch_bounds__(1024) void k_fused(const float* __restrict__ ps,
                                                const float* __restrict__ cnt,
                                                float* __restrict__ out) {
    __shared__ float s_sm[46 * 48];
    __shared__ float hrs[46 * 40];
    __shared__ float t_s[39 * 40];
    __shared__ float vs[32 * 40];
    const int tx = threadIdx.x, ty = threadIdx.y;
    const int tid = ty * 32 + tx;
    const int a = blockIdx.z;
    const int y0 = blockIdx.y * 32, x0 = blockIdx.x * 32;
    const float* pa = ps + (size_t)a * (NH * NW);

    // sm tile: 46x46, coords clamped (clamped entries only feed invalid t)
    for (int idx = tid; idx < 46 * 46; idx += 1024) {
        int r = idx / 46, cc = idx - r * 46;
        int rg = y0 - 7 + r;  rg = rg < 0 ? 0 : (rg > NH - 1 ? NH - 1 : rg);
        int cg = x0 - 7 + cc; cg = cg < 0 ? 0 : (cg > NW - 1 ? NW - 1 : cg);
        int p = rg * NW + cg;
        float s = pa[p] + pa[p + QSTRIDE] + pa[p + 2 * QSTRIDE] + pa[p + 3 * QSTRIDE];
        s_sm[r * 48 + cc] = __expf(s * (1.0f / NB));
    }
    __syncthreads();

    // horizontal 8-sums: hrs[r][c] = sum_j sm[r][c+j], 46x39
    for (int idx = tid; idx < 46 * 39; idx += 1024) {
        int r = idx / 39, cc = idx - r * 39;
        const float* row = &s_sm[r * 48 + cc];
        hrs[r * 40 + cc] = row[0] + row[1] + row[2] + row[3] +
                           row[4] + row[5] + row[6] + row[7];
    }
    __syncthreads();

    // t = c / sc (vertical 8-sum of hrs), zero when (ph,pw) outside [0,248]^2
    const float* ca = cnt + (size_t)a * (HP * WP);
    for (int idx = tid; idx < 39 * 39; idx += 1024) {
        int r = idx / 39, cc = idx - r * 39;
        float sc = 0.f;
        #pragma unroll
        for (int i = 0; i < 8; ++i) sc += hrs[(r + i) * 40 + cc];
        int ph = y0 - 7 + r, pw = x0 - 7 + cc;
        float tv = 0.f;
        if ((unsigned)ph < (unsigned)HP && (unsigned)pw < (unsigned)WP)
            tv = ca[ph * WP + pw] / sc;
        t_s[r * 40 + cc] = tv;
    }
    __syncthreads();

    // vertical 8-sums of t: vs[ty][c] = sum_i t[ty+i][c], 32x39
    for (int idx = tid; idx < 32 * 39; idx += 1024) {
        int r = idx / 39, cc = idx - r * 39;
        float s = 0.f;
        #pragma unroll
        for (int i = 0; i < 8; ++i) s += t_s[(r + i) * 40 + cc];
        vs[r * 40 + cc] = s;
    }
    __syncthreads();

    // out = sm_center * horizontal 8-sum of vs
    float s = 0.f;
    #pragma unroll
    for (int j = 0; j < 8; ++j) s += vs[ty * 40 + tx + j];
    out[((size_t)a * NH + (y0 + ty)) * NW + (x0 + tx)] = s_sm[(ty + 7) * 48 + tx + 7] * s;
}

extern "C" void kernel_launch(void* const* d_in, const int* in_sizes, int n_in,
                              void* d_out, int out_size, void* d_ws, size_t ws_size,
                              hipStream_t stream) {
    const float* x = (const float*)d_in[0];   // (8,64,256,256) f32
    const float* c = (const float*)d_in[1];   // (8,1,249,249)  f32
    float* out = (float*)d_out;               // (8,1,256,256)  f32
    float* ps  = (float*)d_ws;                // 4 partial planes, 8 MB

    k_partial<<<2048, 256, 0, stream>>>(x, ps);
    dim3 grid(NW / 32, NH / 32, NA);          // (8,8,8)
    dim3 block(32, 32);
    k_fused<<<grid, block, 0, stream>>>(ps, c, out);
}

// Round 3
// 198.078 us; speedup vs baseline: 1.0910x; 1.0161x over previous
//
#include <hip/hip_runtime.h>

#define KK 8
#define NA 8
#define NB 64
#define NH 256
#define NW 256
#define HP (NH - KK + 1)   // 249
#define WP (NW - KK + 1)   // 249

// Stage 1: sm[a][y][x] = exp( (1/64) * sum_b x[a][b][y][x] )
// One float4 per thread, full 64-channel reduction. 512 blocks = 2 waves/SIMD;
// unroll keeps ~8-16 float4 loads in flight per wave (>= 8 KB/wave, ~64 KB/CU
// outstanding vs ~9 KB needed to cover 900-cyc HBM latency at 24.6 GB/s/CU).
__global__ __launch_bounds__(256) void k_mean_exp(const float* __restrict__ x,
                                                  float* __restrict__ sm) {
    int tid = blockIdx.x * 256 + threadIdx.x;   // 0 .. A*H*W/4-1
    int a = tid >> 14;                          // H*W/4 = 16384 float4 per image
    int p4 = tid & 16383;
    const float4* xp = (const float4*)(x + (size_t)a * NB * (NH * NW)) + p4;
    float4 acc = {0.f, 0.f, 0.f, 0.f};
    #pragma unroll 16
    for (int b = 0; b < NB; ++b) {
        float4 v = xp[(size_t)b * (NH * NW / 4)];
        acc.x += v.x; acc.y += v.y; acc.z += v.z; acc.w += v.w;
    }
    const float s = 1.0f / NB;
    float4 r;
    r.x = __expf(acc.x * s);
    r.y = __expf(acc.y * s);
    r.z = __expf(acc.z * s);
    r.w = __expf(acc.w * s);
    ((float4*)sm)[tid] = r;
}

// Stage 2 (fused): per 32x32 output tile, stage the 46x46 sm tile (7-halo)
// into LDS, then separable box sums: hrs (horiz 8-sum), t = c/sc with OOB
// zeroed, vs (vert 8-sum of t), out = sm_center * horiz 8-sum of vs.
__global__ __launch_bounds__(1024) void k_fused(const float* __restrict__ sm,
                                                const float* __restrict__ cnt,
                                                float* __restrict__ out) {
    __shared__ float s_sm[46 * 48];
    __shared__ float hrs[46 * 40];
    __shared__ float t_s[39 * 40];
    __shared__ float vs[32 * 40];
    const int tx = threadIdx.x, ty = threadIdx.y;
    const int tid = ty * 32 + tx;
    const int a = blockIdx.z;
    const int y0 = blockIdx.y * 32, x0 = blockIdx.x * 32;
    const float* sa = sm + (size_t)a * (NH * NW);

    // sm tile: 46x46, coords clamped (clamped entries only feed invalid t)
    for (int idx = tid; idx < 46 * 46; idx += 1024) {
        int r = idx / 46, cc = idx - r * 46;
        int rg = y0 - 7 + r;  rg = rg < 0 ? 0 : (rg > NH - 1 ? NH - 1 : rg);
        int cg = x0 - 7 + cc; cg = cg < 0 ? 0 : (cg > NW - 1 ? NW - 1 : cg);
        s_sm[r * 48 + cc] = sa[rg * NW + cg];
    }
    __syncthreads();

    // horizontal 8-sums: hrs[r][c] = sum_j sm[r][c+j], 46x39
    for (int idx = tid; idx < 46 * 39; idx += 1024) {
        int r = idx / 39, cc = idx - r * 39;
        const float* row = &s_sm[r * 48 + cc];
        hrs[r * 40 + cc] = row[0] + row[1] + row[2] + row[3] +
                           row[4] + row[5] + row[6] + row[7];
    }
    __syncthreads();

    // t = c / sc (vertical 8-sum of hrs), zero when (ph,pw) outside valid range
    const float* ca = cnt + (size_t)a * (HP * WP);
    for (int idx = tid; idx < 39 * 39; idx += 1024) {
        int r = idx / 39, cc = idx - r * 39;
        float sc = 0.f;
        #pragma unroll
        for (int i = 0; i < 8; ++i) sc += hrs[(r + i) * 40 + cc];
        int ph = y0 - 7 + r, pw = x0 - 7 + cc;
        float tv = 0.f;
        if ((unsigned)ph < (unsigned)HP && (unsigned)pw < (unsigned)WP)
            tv = ca[ph * WP + pw] / sc;
        t_s[r * 40 + cc] = tv;
    }
    __syncthreads();

    // vertical 8-sums of t: vs[r][c] = sum_i t[r+i][c], 32x39
    for (int idx = tid; idx < 32 * 39; idx += 1024) {
        int r = idx / 39, cc = idx - r * 39;
        float s = 0.f;
        #pragma unroll
        for (int i = 0; i < 8; ++i) s += t_s[(r + i) * 40 + cc];
        vs[r * 40 + cc] = s;
    }
    __syncthreads();

    // out = sm_center * horizontal 8-sum of vs
    float s = 0.f;
    #pragma unroll
    for (int j = 0; j < 8; ++j) s += vs[ty * 40 + tx + j];
    out[((size_t)a * NH + (y0 + ty)) * NW + (x0 + tx)] = s_sm[(ty + 7) * 48 + tx + 7] * s;
}

extern "C" void kernel_launch(void* const* d_in, const int* in_sizes, int n_in,
                              void* d_out, int out_size, void* d_ws, size_t ws_size,
                              hipStream_t stream) {
    const float* x = (const float*)d_in[0];   // (8,64,256,256) f32
    const float* c = (const float*)d_in[1];   // (8,1,249,249)  f32
    float* out = (float*)d_out;               // (8,1,256,256)  f32
    float* sm  = (float*)d_ws;                // 2 MB

    k_mean_exp<<<(NA * NH * NW / 4) / 256, 256, 0, stream>>>(x, sm);
    dim3 grid(NW / 32, NH / 32, NA);          // (8,8,8)
    dim3 block(32, 32);
    k_fused<<<grid, block, 0, stream>>>(sm, c, out);
}